// Round 6
// baseline (132.059 us; speedup 1.0000x reference)
//
#include <hip/hip_runtime.h>
#include <cstdint>
#include <cstddef>

// ---------------- problem constants ----------------
#define NB    32          // batch
#define CI    128         // in channels
#define CO    256         // out channels
#define HW_   56          // spatial
#define HP    58          // padded spatial
#define KTOT  1152        // 128*9 reduction
#define NKT   36          // K-tiles of 32
#define MTOT  (NB * HW_ * HW_)   // 100352 output pixels

static constexpr size_t XP_ELEMS = (size_t)NB * HP * HP * CI;   // 13,776,896
static constexpr size_t WT_ELEMS = (size_t)CO * KTOT;           // 294,912
static constexpr size_t XP_BYTES = XP_ELEMS * 2;
static constexpr size_t WT_BYTES = WT_ELEMS * 2;

typedef __attribute__((ext_vector_type(8)))  short bf16x8;
typedef __attribute__((ext_vector_type(16))) float f32x16;

__device__ __forceinline__ short f32_to_bf16(float f) {
  uint32_t u = __float_as_uint(f);
  uint32_t r = (u + 0x7FFFu + ((u >> 16) & 1u)) >> 16;
  return (short)r;
}

typedef __attribute__((address_space(3))) void       lds_void;
typedef const __attribute__((address_space(1))) void gbl_void;

__device__ __forceinline__ void gload16(const void* g, void* l) {
  // dest = wave-uniform LDS base; HW writes lane's 16B at base + lane*16
  __builtin_amdgcn_global_load_lds((gbl_void*)g, (lds_void*)l, 16, 0, 0);
}

// ---- pre-pass: x NCHW f32 -> padded NHWC bf16; wt OIHW -> [o][kh][kw][c] bf16 ----
__global__ void pad_convert(const float* __restrict__ x, short* __restrict__ xp,
                            const float* __restrict__ wt, short* __restrict__ wbT) {
  __shared__ float lds[CI][57];
  const int blk = blockIdx.x;    // NB*HP = 1856
  const int hp  = blk % HP;
  const int nb  = blk / HP;
  const int tid = threadIdx.x;   // 256

  // fold weight conversion into the first 1152 blocks (1152*256 == WT_ELEMS)
  if (blk < 1152) {
    int idx = blk * 256 + tid;
    int c  = idx & 127;
    int t  = idx >> 7;          // o*9 + kh*3 + kw
    int kw = t % 3;  int t2 = t / 3;
    int kh = t2 % 3; int o  = t2 / 3;
    wbT[idx] = f32_to_bf16(wt[(((size_t)o * CI + c) * 3 + kh) * 3 + kw]);
  }

  const bool interior = (hp >= 1 && hp <= HW_);
  if (interior) {
    const float* src = x + (size_t)nb * CI * HW_ * HW_ + (size_t)(hp - 1) * HW_;
    for (int t = tid; t < CI * HW_; t += 256) {
      int c = t / HW_, w = t - (t / HW_) * HW_;
      lds[c][w] = src[(size_t)c * HW_ * HW_ + w];
    }
  }
  __syncthreads();
  short* dst = xp + (size_t)(nb * HP + hp) * HP * CI;
  for (int t = tid; t < HP * CI / 4; t += 256) {
    const int wp = t >> 5;          // 32 channel-quads per wp
    const int c4 = (t & 31) * 4;
    short4 s;
    if (interior && wp >= 1 && wp <= HW_) {
      s.x = f32_to_bf16(lds[c4 + 0][wp - 1]);
      s.y = f32_to_bf16(lds[c4 + 1][wp - 1]);
      s.z = f32_to_bf16(lds[c4 + 2][wp - 1]);
      s.w = f32_to_bf16(lds[c4 + 3][wp - 1]);
    } else {
      s.x = s.y = s.z = s.w = 0;
    }
    *(short4*)(dst + t * 4) = s;
  }
}

// scalar byte offset into an xp pixel row for K-tile u (tap + channel-quarter)
__device__ __forceinline__ int stage_aoff(int u) {
  const int tap = u >> 2;            // 0..8
  const int cq  = u & 3;             // channel quarter (32 ch)
  const int kh  = tap / 3, kw = tap - kh * 3;
  return ((kh * HP + kw) * CI + cq * 32) * 2;
}

// ---------------- main: implicit GEMM, 256x128 tile, BK=32, 4 waves ----------------
// R6 changes vs R4 (theory: LDS-b128-throughput-bound):
//  * B operand NEVER goes through LDS: each wave global-loads its own B frags
//    to VGPRs, prefetched 1 tile ahead (issued BEFORE the A-stage gloads so the
//    boundary vmcnt(4) confirms them: outstanding after wait = A(v+2) only).
//  * 32x32x16 MFMA (16 instrs/tile instead of 32; better pipe efficiency;
//    acc = 2 x f32x16 x 4 = 128 regs, unchanged).
//  * LDS = A only: 3 buffers x 16KB = 48KB -> 2 blocks/CU.
// A swizzle (verified 0 conflicts R3/R4/R5): LDS 16B-piece pc of row r holds
// global piece pc ^ ((r>>1)&3); pre-swizzled gload source + swizzled ds_read.
__global__ __launch_bounds__(256, 2) void conv_gemm(
    const short* __restrict__ xp, const short* __restrict__ wbT,
    const float* __restrict__ bias, float* __restrict__ out) {
  __shared__ __align__(16) char lds_[3 * 16384];

  const int tid = threadIdx.x;     // 256
  const int l   = tid & 63;
  const int wv  = tid >> 6;        // 0..3
  const int wm  = wv >> 1;         // 0..1  (m half: 128 rows)
  const int wn  = wv & 1;          // 0..1  (oc half: 64 cols)

  // grid 784 = 8 XCDs x 98; chunked bijective swizzle, nt inner (A reuse in L2)
  const int bid = blockIdx.x;
  const int lin = (bid & 7) * 98 + (bid >> 3);
  const int mt  = lin >> 1;
  const int nt  = lin & 1;

  // ---- A staging source pointers (pre-swizzled per rule #21) ----
  // gload g covers rows 64g + 16wv + (l>>2); lane piece (l&3); src piece ^((l>>3)&3)
  const int pcs  = (((l & 3) ^ ((l >> 3) & 3)) << 4);
  const int srow = 16 * wv + (l >> 2);                 // 0..63 per gload group
  const char *aSrc0, *aSrc1, *aSrc2, *aSrc3;
  {
#pragma unroll
    for (int g = 0; g < 4; ++g) {
      int m  = mt * 256 + 64 * g + srow;
      int nb = m / 3136, hw = m - nb * 3136;
      int h = hw / HW_, w = hw - (hw / HW_) * HW_;
      const char* p = (const char*)xp + ((size_t)((nb * HP + h) * HP + w) * CI) * 2 + pcs;
      if (g == 0) aSrc0 = p; else if (g == 1) aSrc1 = p;
      else if (g == 2) aSrc2 = p; else aSrc3 = p;
    }
  }

  // ---- B direct-to-register lane addresses (2 n-frags of 32 oc) ----
  // lane l holds B row oc = base + n*32 + (l&31), k-piece (l>>5)
  const char* bAddr0 = (const char*)wbT +
      (size_t)(nt * 128 + wn * 64 + 0 * 32 + (l & 31)) * (KTOT * 2) + ((l >> 5) * 16);
  const char* bAddr1 = (const char*)wbT +
      (size_t)(nt * 128 + wn * 64 + 1 * 32 + (l & 31)) * (KTOT * 2) + ((l >> 5) * 16);

  // ---- A frag ds_read offsets (swizzled): af[g][kh] at row wm*128+g*32+(l&31),
  //      logical piece p = kh*2 + (l>>5), LDS piece = p ^ ((l>>1)&3)
  const int arow = (wm * 128 + (l & 31)) * 64;
  int aOff[4][2];
#pragma unroll
  for (int g = 0; g < 4; ++g)
#pragma unroll
    for (int kh = 0; kh < 2; ++kh)
      aOff[g][kh] = arow + g * 32 * 64 +
                    ((((kh * 2) + (l >> 5)) ^ ((l >> 1) & 3)) << 4);

  char* B0 = lds_;
  char* B1 = lds_ + 16384;
  char* B2 = lds_ + 32768;

#define STAGE_A(U, BUF)                                                      \
  {                                                                          \
    const int ao_ = stage_aoff(U);                                           \
    gload16(aSrc0 + ao_, (BUF) +         wv * 1024);                         \
    gload16(aSrc1 + ao_, (BUF) +  4096 + wv * 1024);                         \
    gload16(aSrc2 + ao_, (BUF) +  8192 + wv * 1024);                         \
    gload16(aSrc3 + ao_, (BUF) + 12288 + wv * 1024);                         \
  }
// load B frags for K-tile U into BF (bf16x8 BF[2][2]: [n][kh])
#define LOAD_B(U, BF)                                                        \
  {                                                                          \
    const int bo_ = (U) * 64;                                                \
    BF[0][0] = *(const bf16x8*)(bAddr0 + bo_);                               \
    BF[0][1] = *(const bf16x8*)(bAddr0 + bo_ + 32);                          \
    BF[1][0] = *(const bf16x8*)(bAddr1 + bo_);                               \
    BF[1][1] = *(const bf16x8*)(bAddr1 + bo_ + 32);                          \
  }

  f32x16 acc[4][2];
#pragma unroll
  for (int g = 0; g < 4; ++g)
#pragma unroll
    for (int h = 0; h < 2; ++h)
#pragma unroll
      for (int e = 0; e < 16; ++e) acc[g][h][e] = 0.f;

  bf16x8 bfP[2][2], bfQ[2][2];

  // ---- prologue: stage A tiles 0,1; load B tile 0; drain once ----
  STAGE_A(0, B0)
  STAGE_A(1, B1)
  LOAD_B(0, bfP)
  asm volatile("s_waitcnt vmcnt(0)" ::: "memory");
  __builtin_amdgcn_s_barrier();
  __builtin_amdgcn_sched_barrier(0);

// tile v: read A from CUR, MFMA with BFC (loaded last tile), stage A(v+2)->STG,
// load B(v+1)->BFN. Issue order: B first, A-stage second => boundary vmcnt(4)
// leaves only A(v+2) outstanding and confirms B(v+1) + A(v+1).
#define TILE_BODY(V, CUR, STG, BFC, BFN)                                     \
  {                                                                          \
    const int v_ = (V);                                                      \
    if (v_ + 1 < NKT) LOAD_B(v_ + 1, BFN)                                    \
    if (v_ + 2 < NKT) STAGE_A(v_ + 2, STG)                                   \
    bf16x8 af[4][2];                                                         \
    _Pragma("unroll") for (int g = 0; g < 4; ++g)                            \
      _Pragma("unroll") for (int kh = 0; kh < 2; ++kh)                       \
        af[g][kh] = *(const bf16x8*)((CUR) + aOff[g][kh]);                   \
    __builtin_amdgcn_s_setprio(1);                                           \
    _Pragma("unroll") for (int kh = 0; kh < 2; ++kh)                         \
      _Pragma("unroll") for (int g = 0; g < 4; ++g)                          \
        _Pragma("unroll") for (int h = 0; h < 2; ++h)                        \
          acc[g][h] = __builtin_amdgcn_mfma_f32_32x32x16_bf16(               \
              BFC[h][kh], af[g][kh], acc[g][h], 0, 0, 0);                    \
    __builtin_amdgcn_s_setprio(0);                                           \
    if (v_ < NKT - 1) {                                                      \
      if (v_ >= NKT - 3) { asm volatile("s_waitcnt vmcnt(0)" ::: "memory"); }\
      else               { asm volatile("s_waitcnt vmcnt(4)" ::: "memory"); }\
      __builtin_amdgcn_s_barrier();                                          \
      __builtin_amdgcn_sched_barrier(0);                                     \
    }                                                                        \
  }

  // 3-buffer x bf-parity => 6-cycle; NKT = 36
  for (int v6 = 0; v6 < NKT; v6 += 6) {
    TILE_BODY(v6 + 0, B0, B2, bfP, bfQ)
    TILE_BODY(v6 + 1, B1, B0, bfQ, bfP)
    TILE_BODY(v6 + 2, B2, B1, bfP, bfQ)
    TILE_BODY(v6 + 3, B0, B2, bfQ, bfP)
    TILE_BODY(v6 + 4, B1, B0, bfP, bfQ)
    TILE_BODY(v6 + 5, B2, B1, bfQ, bfP)
  }
#undef TILE_BODY
#undef STAGE_A
#undef LOAD_B

  // ---- epilogue: 32x32 C/D layout (swapped operands): D row = oc, col = m.
  //      col = lane&31 (= m offset), row = (reg&3) + 8*(reg>>2) + 4*(lane>>5).
  const int ocB = nt * 128 + wn * 64 + 4 * (l >> 5);
  float bb[2][16];
#pragma unroll
  for (int h = 0; h < 2; ++h)
#pragma unroll
    for (int q = 0; q < 4; ++q)
#pragma unroll
      for (int j = 0; j < 4; ++j)
        bb[h][q * 4 + j] = bias[ocB + h * 32 + q * 8 + j];
#pragma unroll
  for (int g = 0; g < 4; ++g) {
    const int mB = mt * 256 + wm * 128 + g * 32;   // 32-aligned: never crosses 3136
    const int nb = mB / 3136;
    const int hw = mB - nb * 3136 + (l & 31);
    float* op = out + (size_t)nb * CO * 3136 + hw;
#pragma unroll
    for (int h = 0; h < 2; ++h) {
#pragma unroll
      for (int q = 0; q < 4; ++q)
#pragma unroll
        for (int j = 0; j < 4; ++j) {
          const int oc = ocB + h * 32 + q * 8 + j;
          op[(size_t)oc * 3136] = acc[g][h][q * 4 + j] + bb[h][q * 4 + j];
        }
    }
  }
}

// ---------------- fallback (ws too small): naive direct conv ----------------
__global__ void conv_naive(const float* __restrict__ x, const float* __restrict__ wt,
                           const float* __restrict__ bias, float* __restrict__ out) {
  const int idx = blockIdx.x * 256 + threadIdx.x;
  if (idx >= NB * CO * 3136) return;
  const int w  = idx % HW_;
  const int h  = (idx / HW_) % HW_;
  const int oc = (idx / 3136) % CO;
  const int nb = idx / (3136 * CO);
  float s = bias[oc];
  for (int c = 0; c < CI; ++c)
    for (int kh = 0; kh < 3; ++kh) {
      const int ih = h + kh - 1;
      if (ih < 0 || ih >= HW_) continue;
      for (int kw = 0; kw < 3; ++kw) {
        const int iw = w + kw - 1;
        if (iw < 0 || iw >= HW_) continue;
        s += x[((size_t)(nb * CI + c) * HW_ + ih) * HW_ + iw] *
             wt[(((size_t)oc * CI + c) * 3 + kh) * 3 + kw];
      }
    }
  out[idx] = s;
}

extern "C" void kernel_launch(void* const* d_in, const int* in_sizes, int n_in,
                              void* d_out, int out_size, void* d_ws, size_t ws_size,
                              hipStream_t stream) {
  const float* x    = (const float*)d_in[0];
  const float* wt   = (const float*)d_in[1];
  const float* bias = (const float*)d_in[2];
  float* out        = (float*)d_out;

  if (ws_size < XP_BYTES + WT_BYTES) {
    conv_naive<<<(NB * CO * 3136 + 255) / 256, 256, 0, stream>>>(x, wt, bias, out);
    return;
  }

  short* xp  = (short*)d_ws;
  short* wbT = (short*)((char*)d_ws + XP_BYTES);

  pad_convert<<<NB * HP, 256, 0, stream>>>(x, xp, wt, wbT);
  conv_gemm<<<(MTOT / 256) * 2, 256, 0, stream>>>(xp, wbT, bias, out);
}